// Round 3
// baseline (1232.496 us; speedup 1.0000x reference)
//
#include <hip/hip_runtime.h>
#include <cstdint>

// ---------------- helpers ----------------

__global__ void zero_kernel(int* __restrict__ p, int n) {
    int i = blockIdx.x * 256 + threadIdx.x;
    if (i < n) p[i] = 0;
}

// ---------------- CSR build (by dst), reused for both layers ----------------
// NOTE: edge_index arrives as int32 (JAX default x64=False), NOT int64.

__global__ void hist_kernel(const int* __restrict__ eidx, int E, int* __restrict__ counts) {
    int e = blockIdx.x * 256 + threadIdx.x;
    if (e < E) {
        int d = eidx[E + e];
        atomicAdd(&counts[d], 1);
    }
}

__global__ void scan_block_kernel(const int* __restrict__ counts, int* __restrict__ offsets,
                                  int* __restrict__ bsum, int n) {
    __shared__ int s[256];
    int i = blockIdx.x * 256 + threadIdx.x;
    int v = (i < n) ? counts[i] : 0;
    s[threadIdx.x] = v;
    __syncthreads();
    for (int d = 1; d < 256; d <<= 1) {
        int t = (threadIdx.x >= d) ? s[threadIdx.x - d] : 0;
        __syncthreads();
        s[threadIdx.x] += t;
        __syncthreads();
    }
    if (i < n) offsets[i] = s[threadIdx.x] - v;  // exclusive within block
    if (threadIdx.x == 255) bsum[blockIdx.x] = s[255];
}

__global__ void scan_top_kernel(const int* __restrict__ bsum, int* __restrict__ bscan,
                                int nb, int* __restrict__ offsets, int n, int E) {
    __shared__ int s[512];
    int v = (threadIdx.x < nb) ? bsum[threadIdx.x] : 0;
    s[threadIdx.x] = v;
    __syncthreads();
    for (int d = 1; d < 512; d <<= 1) {
        int t = (threadIdx.x >= d) ? s[threadIdx.x - d] : 0;
        __syncthreads();
        s[threadIdx.x] += t;
        __syncthreads();
    }
    if (threadIdx.x < nb) bscan[threadIdx.x] = s[threadIdx.x] - v;
    if (threadIdx.x == 0) offsets[n] = E;
}

__global__ void scan_add_kernel(int* __restrict__ offsets, const int* __restrict__ bscan,
                                int* __restrict__ cursor, int n) {
    int i = blockIdx.x * 256 + threadIdx.x;
    if (i < n) {
        int o = offsets[i] + bscan[blockIdx.x];
        offsets[i] = o;
        cursor[i] = o;
    }
}

__global__ void scatter_kernel(const int* __restrict__ eidx, int E,
                               int* __restrict__ cursor, int* __restrict__ sorted_src) {
    int e = blockIdx.x * 256 + threadIdx.x;
    if (e < E) {
        int sidx = eidx[e];
        int d = eidx[E + e];
        int pos = atomicAdd(&cursor[d], 1);
        sorted_src[pos] = sidx;
    }
}

// ---------------- Fused GIN layer: aggregate + 2-layer MLP ----------------
// One wave (64 threads) per block, 64 nodes per block.
// Phase A: wave-per-node, lane = feature -> coalesced gather of neighbor rows;
//          result transposed into LDS with stride 65 (bank-conflict-free both ways).
// Phase B/C: thread-per-node MLP. Weight indices are wave-uniform -> s_load;
//          inner loops are pure v_fmac_f32.

template <int KIN, int KMID, int KOUT, bool RELU_OUT>
__global__ __launch_bounds__(64) void gin_layer_kernel(
    const float* __restrict__ h, const int* __restrict__ offs, const int* __restrict__ srcs,
    const float* __restrict__ eps, const float* __restrict__ Wa, const float* __restrict__ ba,
    const float* __restrict__ Wb, const float* __restrict__ bb, float* __restrict__ out, int n) {
    constexpr int ST = 65;  // transpose stride: bank = (k + m) % 32 -> conflict-free
    constexpr int LROWS = (KIN > KMID ? KIN : KMID);
    __shared__ float lds[LROWS * ST];
    int tid = threadIdx.x;
    int base = blockIdx.x * 64;
    float scale = 1.0f + eps[0];

    // ---- Phase A: aggregation, one node at a time, whole wave cooperates ----
    int nNodes = min(64, n - base);
    for (int m = 0; m < nNodes; ++m) {
        int node = base + m;
        int e0 = offs[node], e1 = offs[node + 1];
        if (KIN == 64) {
            float acc = scale * h[(size_t)node * 64 + tid];
            for (int e = e0; e < e1; ++e) acc += h[(size_t)srcs[e] * 64 + tid];
            lds[tid * ST + m] = acc;
        } else {  // KIN == 128: lane handles features (2*tid, 2*tid+1)
            const float2* h2 = (const float2*)h;
            float2 a = h2[(size_t)node * 64 + tid];
            float ax = scale * a.x, ay = scale * a.y;
            for (int e = e0; e < e1; ++e) {
                float2 v = h2[(size_t)srcs[e] * 64 + tid];
                ax += v.x;
                ay += v.y;
            }
            lds[(2 * tid) * ST + m] = ax;
            lds[(2 * tid + 1) * ST + m] = ay;
        }
    }
    __syncthreads();

    // ---- Phase B: t = relu(z @ Wa + ba), thread-per-node ----
    int node = base + tid;
    float t[KMID];
#pragma unroll
    for (int j = 0; j < KMID; ++j) t[j] = 0.0f;
    for (int k = 0; k < KIN; ++k) {
        float zk = lds[k * ST + tid];
#pragma unroll
        for (int j = 0; j < KMID; ++j) t[j] = __builtin_fmaf(zk, Wa[k * KMID + j], t[j]);
    }
#pragma unroll
    for (int j = 0; j < KMID; ++j) t[j] = fmaxf(t[j] + ba[j], 0.0f);

    __syncthreads();  // z region dead; reuse LDS for t
#pragma unroll
    for (int j = 0; j < KMID; ++j) lds[j * ST + tid] = t[j];

    // ---- Phase C: out = t @ Wb + bb (+ optional relu) ----
    float hacc[KOUT];
#pragma unroll
    for (int j = 0; j < KOUT; ++j) hacc[j] = 0.0f;
    for (int k = 0; k < KMID; ++k) {
        float tk = lds[k * ST + tid];
#pragma unroll
        for (int j = 0; j < KOUT; ++j) hacc[j] = __builtin_fmaf(tk, Wb[k * KOUT + j], hacc[j]);
    }

    if (node < n) {
        float4* orow = (float4*)(out + (size_t)node * KOUT);
#pragma unroll
        for (int j4 = 0; j4 < KOUT / 4; ++j4) {
            float4 v;
            v.x = hacc[4 * j4 + 0] + bb[4 * j4 + 0];
            v.y = hacc[4 * j4 + 1] + bb[4 * j4 + 1];
            v.z = hacc[4 * j4 + 2] + bb[4 * j4 + 2];
            v.w = hacc[4 * j4 + 3] + bb[4 * j4 + 3];
            if (RELU_OUT) {
                v.x = fmaxf(v.x, 0.0f);
                v.y = fmaxf(v.y, 0.0f);
                v.z = fmaxf(v.z, 0.0f);
                v.w = fmaxf(v.w, 0.0f);
            }
            orow[j4] = v;
        }
    }
}

// ---------------- Launch ----------------

extern "C" void kernel_launch(void* const* d_in, const int* in_sizes, int n_in,
                              void* d_out, int out_size, void* d_ws, size_t ws_size,
                              hipStream_t stream) {
    const float* x = (const float*)d_in[0];
    const int* eidx = (const int*)d_in[1];  // int32! (JAX x64 disabled)
    const float* eps1 = (const float*)d_in[2];
    const float* eps2 = (const float*)d_in[3];
    const float* W1a = (const float*)d_in[4];
    const float* b1a = (const float*)d_in[5];
    const float* W1b = (const float*)d_in[6];
    const float* b1b = (const float*)d_in[7];
    const float* W2a = (const float*)d_in[8];
    const float* b2a = (const float*)d_in[9];
    const float* W2b = (const float*)d_in[10];
    const float* b2b = (const float*)d_in[11];
    float* out = (float*)d_out;

    int N = in_sizes[0] / 64;
    int E = in_sizes[1] / 2;

    // Scratch layout (~55.2 MB total): CSR (~4 MB) + h1 (51.2 MB). No z buffer.
    char* p = (char*)d_ws;
    auto alloc = [&](size_t bytes) {
        char* r = p;
        p += (bytes + 255) & ~(size_t)255;
        return r;
    };
    int* counts = (int*)alloc((size_t)N * 4);  // reused as cursor after scan
    int* offsets = (int*)alloc((size_t)(N + 1) * 4);
    int* bsum = (int*)alloc(512 * 4);
    int* bscan = (int*)alloc(512 * 4);
    int* sorted_src = (int*)alloc((size_t)E * 4);
    float* h1 = (float*)alloc((size_t)N * 128 * 4);

    int eb = (E + 255) / 256;
    int nb = (N + 255) / 256;  // 391 <= 512, fits scan_top
    int gb = (N + 63) / 64;

    zero_kernel<<<nb, 256, 0, stream>>>(counts, N);
    hist_kernel<<<eb, 256, 0, stream>>>(eidx, E, counts);
    scan_block_kernel<<<nb, 256, 0, stream>>>(counts, offsets, bsum, N);
    scan_top_kernel<<<1, 512, 0, stream>>>(bsum, bscan, nb, offsets, N, E);
    scan_add_kernel<<<nb, 256, 0, stream>>>(offsets, bscan, counts, N);  // counts becomes cursor
    scatter_kernel<<<eb, 256, 0, stream>>>(eidx, E, counts, sorted_src);

    gin_layer_kernel<64, 128, 128, true>
        <<<gb, 64, 0, stream>>>(x, offsets, sorted_src, eps1, W1a, b1a, W1b, b1b, h1, N);
    gin_layer_kernel<128, 128, 64, false>
        <<<gb, 64, 0, stream>>>(h1, offsets, sorted_src, eps2, W2a, b2a, W2b, b2b, out, N);
}

// Round 4
// 943.644 us; speedup vs baseline: 1.3061x; 1.3061x over previous
//
#include <hip/hip_runtime.h>
#include <cstdint>

// ---------------- helpers ----------------

__global__ void zero_kernel(int* __restrict__ p, int n) {
    int i = blockIdx.x * 256 + threadIdx.x;
    if (i < n) p[i] = 0;
}

// ---------------- CSR build (by dst), reused for both layers ----------------
// edge_index arrives as int32 (JAX default x64=False).

__global__ void hist_kernel(const int* __restrict__ eidx, int E, int* __restrict__ counts) {
    int e = blockIdx.x * 256 + threadIdx.x;
    if (e < E) atomicAdd(&counts[eidx[E + e]], 1);
}

__global__ void scan_block_kernel(const int* __restrict__ counts, int* __restrict__ offsets,
                                  int* __restrict__ bsum, int n) {
    __shared__ int s[256];
    int i = blockIdx.x * 256 + threadIdx.x;
    int v = (i < n) ? counts[i] : 0;
    s[threadIdx.x] = v;
    __syncthreads();
    for (int d = 1; d < 256; d <<= 1) {
        int t = (threadIdx.x >= d) ? s[threadIdx.x - d] : 0;
        __syncthreads();
        s[threadIdx.x] += t;
        __syncthreads();
    }
    if (i < n) offsets[i] = s[threadIdx.x] - v;  // exclusive within block
    if (threadIdx.x == 255) bsum[blockIdx.x] = s[255];
}

__global__ void scan_top_kernel(const int* __restrict__ bsum, int* __restrict__ bscan,
                                int nb, int* __restrict__ offsets, int n, int E) {
    __shared__ int s[512];
    int v = (threadIdx.x < nb) ? bsum[threadIdx.x] : 0;
    s[threadIdx.x] = v;
    __syncthreads();
    for (int d = 1; d < 512; d <<= 1) {
        int t = (threadIdx.x >= d) ? s[threadIdx.x - d] : 0;
        __syncthreads();
        s[threadIdx.x] += t;
        __syncthreads();
    }
    if (threadIdx.x < nb) bscan[threadIdx.x] = s[threadIdx.x] - v;
    if (threadIdx.x == 0) offsets[n] = E;
}

__global__ void scan_add_kernel(int* __restrict__ offsets, const int* __restrict__ bscan,
                                int* __restrict__ cursor, int n) {
    int i = blockIdx.x * 256 + threadIdx.x;
    if (i < n) {
        int o = offsets[i] + bscan[blockIdx.x];
        offsets[i] = o;
        cursor[i] = o;
    }
}

__global__ void scatter_kernel(const int* __restrict__ eidx, int E,
                               int* __restrict__ cursor, int* __restrict__ sorted_src) {
    int e = blockIdx.x * 256 + threadIdx.x;
    if (e < E) {
        int pos = atomicAdd(&cursor[eidx[E + e]], 1);
        sorted_src[pos] = eidx[e];
    }
}

// ---------------- Fused GIN layer: aggregate + 2-layer MLP ----------------
// Block = 256 threads (4 waves), 64 nodes per block.
// Phase A: wave w gathers for nodes [16w,16w+16); lane = feature; edge loop
//          unrolled x4 so 4-8 row gathers are in flight per wave. Result is
//          transposed into LDS with row stride 65 (2-way banks = free).
// Phase B/C: thread = (node = lane, out-quarter = wave). Weight/bias indices
//          are wave-uniform -> scalar loads; inner loops pure v_fmac_f32.
// z region and t region share LDS (barrier-separated).

template <int KIN, int KMID, int KOUT, bool RELU_OUT>
__global__ __launch_bounds__(256) void gin_layer_kernel(
    const float* __restrict__ h, const int* __restrict__ offs, const int* __restrict__ srcs,
    const float* __restrict__ eps, const float* __restrict__ Wa, const float* __restrict__ ba,
    const float* __restrict__ Wb, const float* __restrict__ bb, float* __restrict__ out, int n) {
    constexpr int ST = 65;  // bank = (row + m) % 32 -> worst 2-way (free)
    constexpr int LROWS = (KIN > KMID ? KIN : KMID);
    __shared__ float lds[LROWS * ST];
    const int tid = threadIdx.x;
    const int lane = tid & 63;
    const int wave = tid >> 6;
    const int base = blockIdx.x * 64;
    const float scale = 1.0f + eps[0];

    // ---- Phase A: gather + transpose, 16 nodes per wave ----
    for (int mi = 0; mi < 16; ++mi) {
        const int m = wave * 16 + mi;
        const int node = base + m;
        if (node >= n) break;
        const int e0 = offs[node], e1 = offs[node + 1];
        if (KIN == 64) {
            float acc = scale * h[(size_t)node * 64 + lane];
            float a0 = 0.f, a1 = 0.f, a2 = 0.f, a3 = 0.f;
            int e = e0;
            for (; e + 4 <= e1; e += 4) {
                int s0 = srcs[e], s1 = srcs[e + 1], s2 = srcs[e + 2], s3 = srcs[e + 3];
                a0 += h[(size_t)s0 * 64 + lane];
                a1 += h[(size_t)s1 * 64 + lane];
                a2 += h[(size_t)s2 * 64 + lane];
                a3 += h[(size_t)s3 * 64 + lane];
            }
            for (; e < e1; ++e) acc += h[(size_t)srcs[e] * 64 + lane];
            acc += (a0 + a1) + (a2 + a3);
            lds[lane * ST + m] = acc;
        } else {  // KIN == 128: lane covers features {lane, lane+64}
            const float* hr = h + (size_t)node * 128;
            float accx = scale * hr[lane];
            float accy = scale * hr[64 + lane];
            float x0 = 0.f, x1 = 0.f, x2 = 0.f, x3 = 0.f;
            float y0 = 0.f, y1 = 0.f, y2 = 0.f, y3 = 0.f;
            int e = e0;
            for (; e + 4 <= e1; e += 4) {
                const float* r0 = h + (size_t)srcs[e] * 128;
                const float* r1 = h + (size_t)srcs[e + 1] * 128;
                const float* r2 = h + (size_t)srcs[e + 2] * 128;
                const float* r3 = h + (size_t)srcs[e + 3] * 128;
                x0 += r0[lane];
                y0 += r0[64 + lane];
                x1 += r1[lane];
                y1 += r1[64 + lane];
                x2 += r2[lane];
                y2 += r2[64 + lane];
                x3 += r3[lane];
                y3 += r3[64 + lane];
            }
            for (; e < e1; ++e) {
                const float* r = h + (size_t)srcs[e] * 128;
                accx += r[lane];
                accy += r[64 + lane];
            }
            accx += (x0 + x1) + (x2 + x3);
            accy += (y0 + y1) + (y2 + y3);
            lds[lane * ST + m] = accx;
            lds[(64 + lane) * ST + m] = accy;
        }
    }
    __syncthreads();

    // ---- Phase B: t = relu(z @ Wa + ba); thread = (node=lane, quarter=wave) ----
    const int m = lane;
    const int node = base + m;
    constexpr int JB = KMID / 4;
    float t[JB];
#pragma unroll
    for (int j = 0; j < JB; ++j) t[j] = 0.0f;
    for (int k = 0; k < KIN; ++k) {
        const float zk = lds[k * ST + m];
        const float* wrow = Wa + k * KMID + wave * JB;
#pragma unroll
        for (int j = 0; j < JB; ++j) t[j] = __builtin_fmaf(zk, wrow[j], t[j]);
    }
#pragma unroll
    for (int j = 0; j < JB; ++j) t[j] = fmaxf(t[j] + ba[wave * JB + j], 0.0f);

    __syncthreads();  // all z reads done; reuse LDS for t
#pragma unroll
    for (int j = 0; j < JB; ++j) lds[(wave * JB + j) * ST + m] = t[j];
    __syncthreads();

    // ---- Phase C: out = t @ Wb + bb (+ optional relu) ----
    constexpr int JC = KOUT / 4;
    float o[JC];
#pragma unroll
    for (int j = 0; j < JC; ++j) o[j] = 0.0f;
    for (int k = 0; k < KMID; ++k) {
        const float tk = lds[k * ST + m];
        const float* wrow = Wb + k * KOUT + wave * JC;
#pragma unroll
        for (int j = 0; j < JC; ++j) o[j] = __builtin_fmaf(tk, wrow[j], o[j]);
    }

    if (node < n) {
        float4* orow = (float4*)(out + (size_t)node * KOUT + wave * JC);
#pragma unroll
        for (int j4 = 0; j4 < JC / 4; ++j4) {
            float4 v;
            v.x = o[4 * j4 + 0] + bb[wave * JC + 4 * j4 + 0];
            v.y = o[4 * j4 + 1] + bb[wave * JC + 4 * j4 + 1];
            v.z = o[4 * j4 + 2] + bb[wave * JC + 4 * j4 + 2];
            v.w = o[4 * j4 + 3] + bb[wave * JC + 4 * j4 + 3];
            if (RELU_OUT) {
                v.x = fmaxf(v.x, 0.0f);
                v.y = fmaxf(v.y, 0.0f);
                v.z = fmaxf(v.z, 0.0f);
                v.w = fmaxf(v.w, 0.0f);
            }
            orow[j4] = v;
        }
    }
}

// ---------------- Launch ----------------

extern "C" void kernel_launch(void* const* d_in, const int* in_sizes, int n_in,
                              void* d_out, int out_size, void* d_ws, size_t ws_size,
                              hipStream_t stream) {
    const float* x = (const float*)d_in[0];
    const int* eidx = (const int*)d_in[1];  // int32 (JAX x64 disabled)
    const float* eps1 = (const float*)d_in[2];
    const float* eps2 = (const float*)d_in[3];
    const float* W1a = (const float*)d_in[4];
    const float* b1a = (const float*)d_in[5];
    const float* W1b = (const float*)d_in[6];
    const float* b1b = (const float*)d_in[7];
    const float* W2a = (const float*)d_in[8];
    const float* b2a = (const float*)d_in[9];
    const float* W2b = (const float*)d_in[10];
    const float* b2b = (const float*)d_in[11];
    float* out = (float*)d_out;

    int N = in_sizes[0] / 64;
    int E = in_sizes[1] / 2;

    char* p = (char*)d_ws;
    auto alloc = [&](size_t bytes) {
        char* r = p;
        p += (bytes + 255) & ~(size_t)255;
        return r;
    };
    int* counts = (int*)alloc((size_t)N * 4);  // reused as cursor after scan
    int* offsets = (int*)alloc((size_t)(N + 1) * 4);
    int* bsum = (int*)alloc(512 * 4);
    int* bscan = (int*)alloc(512 * 4);
    int* sorted_src = (int*)alloc((size_t)E * 4);
    float* h1 = (float*)alloc((size_t)N * 128 * 4);

    int eb = (E + 255) / 256;
    int nb = (N + 255) / 256;  // 391 <= 512, fits scan_top
    int gb = (N + 63) / 64;

    zero_kernel<<<nb, 256, 0, stream>>>(counts, N);
    hist_kernel<<<eb, 256, 0, stream>>>(eidx, E, counts);
    scan_block_kernel<<<nb, 256, 0, stream>>>(counts, offsets, bsum, N);
    scan_top_kernel<<<1, 512, 0, stream>>>(bsum, bscan, nb, offsets, N, E);
    scan_add_kernel<<<nb, 256, 0, stream>>>(offsets, bscan, counts, N);  // counts -> cursor
    scatter_kernel<<<eb, 256, 0, stream>>>(eidx, E, counts, sorted_src);

    gin_layer_kernel<64, 128, 128, true>
        <<<gb, 256, 0, stream>>>(x, offsets, sorted_src, eps1, W1a, b1a, W1b, b1b, h1, N);
    gin_layer_kernel<128, 128, 64, false>
        <<<gb, 256, 0, stream>>>(h1, offsets, sorted_src, eps2, W2a, b2a, W2b, b2b, out, N);
}

// Round 5
// 936.407 us; speedup vs baseline: 1.3162x; 1.0077x over previous
//
#include <hip/hip_runtime.h>
#include <cstdint>

// ---------------- helpers ----------------

__global__ void zero_kernel(int* __restrict__ p, int n) {
    int i = blockIdx.x * 256 + threadIdx.x;
    if (i < n) p[i] = 0;
}

// ---------------- CSR build (by dst), reused for both layers ----------------
// edge_index arrives as int32 (JAX default x64=False).

__global__ void hist_kernel(const int* __restrict__ eidx, int E, int* __restrict__ counts) {
    int e = blockIdx.x * 256 + threadIdx.x;
    if (e < E) atomicAdd(&counts[eidx[E + e]], 1);
}

__global__ void scan_block_kernel(const int* __restrict__ counts, int* __restrict__ offsets,
                                  int* __restrict__ bsum, int n) {
    __shared__ int s[256];
    int i = blockIdx.x * 256 + threadIdx.x;
    int v = (i < n) ? counts[i] : 0;
    s[threadIdx.x] = v;
    __syncthreads();
    for (int d = 1; d < 256; d <<= 1) {
        int t = (threadIdx.x >= d) ? s[threadIdx.x - d] : 0;
        __syncthreads();
        s[threadIdx.x] += t;
        __syncthreads();
    }
    if (i < n) offsets[i] = s[threadIdx.x] - v;  // exclusive within block
    if (threadIdx.x == 255) bsum[blockIdx.x] = s[255];
}

__global__ void scan_top_kernel(const int* __restrict__ bsum, int* __restrict__ bscan,
                                int nb, int* __restrict__ offsets, int n, int E) {
    __shared__ int s[512];
    int v = (threadIdx.x < nb) ? bsum[threadIdx.x] : 0;
    s[threadIdx.x] = v;
    __syncthreads();
    for (int d = 1; d < 512; d <<= 1) {
        int t = (threadIdx.x >= d) ? s[threadIdx.x - d] : 0;
        __syncthreads();
        s[threadIdx.x] += t;
        __syncthreads();
    }
    if (threadIdx.x < nb) bscan[threadIdx.x] = s[threadIdx.x] - v;
    if (threadIdx.x == 0) offsets[n] = E;
}

__global__ void scan_add_kernel(int* __restrict__ offsets, const int* __restrict__ bscan,
                                int* __restrict__ cursor, int n) {
    int i = blockIdx.x * 256 + threadIdx.x;
    if (i < n) {
        int o = offsets[i] + bscan[blockIdx.x];
        offsets[i] = o;
        cursor[i] = o;
    }
}

__global__ void scatter_kernel(const int* __restrict__ eidx, int E,
                               int* __restrict__ cursor, int* __restrict__ sorted_src) {
    int e = blockIdx.x * 256 + threadIdx.x;
    if (e < E) {
        int pos = atomicAdd(&cursor[eidx[E + e]], 1);
        sorted_src[pos] = eidx[e];
    }
}

// ---------------- Fused GIN layer: aggregate + 2-layer MLP ----------------
// Block = 256 threads (4 waves), 64 nodes per block.
// Phase A: wave w gathers for nodes [16w,16w+16); lane = feature; edge loop
//          unrolled x4. Result transposed into LDS, row stride 65 (2-way = free).
// Phase B/C: thread = (node = lane, out-quarter = wave). Weight indices are
//          wave-uniform -> scalar loads; inner loops pure v_fmac_f32.
// CRITICAL: k-loops carry "#pragma unroll 2" — full unroll produced ~40 KB of
//          straight-line code and made R4 instruction-fetch bound (layer1 and
//          layer2 ran in IDENTICAL time = static inst count, not data volume).

template <int KIN, int KMID, int KOUT, bool RELU_OUT>
__global__ __launch_bounds__(256) void gin_layer_kernel(
    const float* __restrict__ h, const int* __restrict__ offs, const int* __restrict__ srcs,
    const float* __restrict__ eps, const float* __restrict__ Wa, const float* __restrict__ ba,
    const float* __restrict__ Wb, const float* __restrict__ bb, float* __restrict__ out, int n) {
    constexpr int ST = 65;  // bank = (row + m) % 32 -> worst 2-way (free)
    constexpr int LROWS = (KIN > KMID ? KIN : KMID);
    __shared__ float lds[LROWS * ST];
    const int tid = threadIdx.x;
    const int lane = tid & 63;
    const int wave = tid >> 6;
    const int base = blockIdx.x * 64;
    const float scale = 1.0f + eps[0];

    // ---- Phase A: gather + transpose, 16 nodes per wave ----
    for (int mi = 0; mi < 16; ++mi) {
        const int m = wave * 16 + mi;
        const int node = base + m;
        if (node >= n) break;
        const int e0 = offs[node], e1 = offs[node + 1];
        if (KIN == 64) {
            float acc = scale * h[(size_t)node * 64 + lane];
            float a0 = 0.f, a1 = 0.f, a2 = 0.f, a3 = 0.f;
            int e = e0;
            for (; e + 4 <= e1; e += 4) {
                int s0 = srcs[e], s1 = srcs[e + 1], s2 = srcs[e + 2], s3 = srcs[e + 3];
                a0 += h[(size_t)s0 * 64 + lane];
                a1 += h[(size_t)s1 * 64 + lane];
                a2 += h[(size_t)s2 * 64 + lane];
                a3 += h[(size_t)s3 * 64 + lane];
            }
            for (; e < e1; ++e) acc += h[(size_t)srcs[e] * 64 + lane];
            acc += (a0 + a1) + (a2 + a3);
            lds[lane * ST + m] = acc;
        } else {  // KIN == 128: lane covers features {lane, lane+64}
            const float* hr = h + (size_t)node * 128;
            float accx = scale * hr[lane];
            float accy = scale * hr[64 + lane];
            float x0 = 0.f, x1 = 0.f, x2 = 0.f, x3 = 0.f;
            float y0 = 0.f, y1 = 0.f, y2 = 0.f, y3 = 0.f;
            int e = e0;
            for (; e + 4 <= e1; e += 4) {
                const float* r0 = h + (size_t)srcs[e] * 128;
                const float* r1 = h + (size_t)srcs[e + 1] * 128;
                const float* r2 = h + (size_t)srcs[e + 2] * 128;
                const float* r3 = h + (size_t)srcs[e + 3] * 128;
                x0 += r0[lane];
                y0 += r0[64 + lane];
                x1 += r1[lane];
                y1 += r1[64 + lane];
                x2 += r2[lane];
                y2 += r2[64 + lane];
                x3 += r3[lane];
                y3 += r3[64 + lane];
            }
            for (; e < e1; ++e) {
                const float* r = h + (size_t)srcs[e] * 128;
                accx += r[lane];
                accy += r[64 + lane];
            }
            accx += (x0 + x1) + (x2 + x3);
            accy += (y0 + y1) + (y2 + y3);
            lds[lane * ST + m] = accx;
            lds[(64 + lane) * ST + m] = accy;
        }
    }
    __syncthreads();

    // ---- Phase B: t = relu(z @ Wa + ba); thread = (node=lane, quarter=wave) ----
    const int m = lane;
    const int node = base + m;
    constexpr int JB = KMID / 4;
    float t[JB];
#pragma unroll
    for (int j = 0; j < JB; ++j) t[j] = 0.0f;
#pragma unroll 2
    for (int k = 0; k < KIN; ++k) {
        const float zk = lds[k * ST + m];
        const float* wrow = Wa + k * KMID + wave * JB;
#pragma unroll
        for (int j = 0; j < JB; ++j) t[j] = __builtin_fmaf(zk, wrow[j], t[j]);
    }
#pragma unroll
    for (int j = 0; j < JB; ++j) t[j] = fmaxf(t[j] + ba[wave * JB + j], 0.0f);

    __syncthreads();  // all z reads done; reuse LDS for t
#pragma unroll
    for (int j = 0; j < JB; ++j) lds[(wave * JB + j) * ST + m] = t[j];
    __syncthreads();

    // ---- Phase C: out = t @ Wb + bb (+ optional relu) ----
    constexpr int JC = KOUT / 4;
    float o[JC];
#pragma unroll
    for (int j = 0; j < JC; ++j) o[j] = 0.0f;
#pragma unroll 2
    for (int k = 0; k < KMID; ++k) {
        const float tk = lds[k * ST + m];
        const float* wrow = Wb + k * KOUT + wave * JC;
#pragma unroll
        for (int j = 0; j < JC; ++j) o[j] = __builtin_fmaf(tk, wrow[j], o[j]);
    }

    if (node < n) {
        float4* orow = (float4*)(out + (size_t)node * KOUT + wave * JC);
#pragma unroll
        for (int j4 = 0; j4 < JC / 4; ++j4) {
            float4 v;
            v.x = o[4 * j4 + 0] + bb[wave * JC + 4 * j4 + 0];
            v.y = o[4 * j4 + 1] + bb[wave * JC + 4 * j4 + 1];
            v.z = o[4 * j4 + 2] + bb[wave * JC + 4 * j4 + 2];
            v.w = o[4 * j4 + 3] + bb[wave * JC + 4 * j4 + 3];
            if (RELU_OUT) {
                v.x = fmaxf(v.x, 0.0f);
                v.y = fmaxf(v.y, 0.0f);
                v.z = fmaxf(v.z, 0.0f);
                v.w = fmaxf(v.w, 0.0f);
            }
            orow[j4] = v;
        }
    }
}

// ---------------- Launch ----------------

extern "C" void kernel_launch(void* const* d_in, const int* in_sizes, int n_in,
                              void* d_out, int out_size, void* d_ws, size_t ws_size,
                              hipStream_t stream) {
    const float* x = (const float*)d_in[0];
    const int* eidx = (const int*)d_in[1];  // int32 (JAX x64 disabled)
    const float* eps1 = (const float*)d_in[2];
    const float* eps2 = (const float*)d_in[3];
    const float* W1a = (const float*)d_in[4];
    const float* b1a = (const float*)d_in[5];
    const float* W1b = (const float*)d_in[6];
    const float* b1b = (const float*)d_in[7];
    const float* W2a = (const float*)d_in[8];
    const float* b2a = (const float*)d_in[9];
    const float* W2b = (const float*)d_in[10];
    const float* b2b = (const float*)d_in[11];
    float* out = (float*)d_out;

    int N = in_sizes[0] / 64;
    int E = in_sizes[1] / 2;

    char* p = (char*)d_ws;
    auto alloc = [&](size_t bytes) {
        char* r = p;
        p += (bytes + 255) & ~(size_t)255;
        return r;
    };
    int* counts = (int*)alloc((size_t)N * 4);  // reused as cursor after scan
    int* offsets = (int*)alloc((size_t)(N + 1) * 4);
    int* bsum = (int*)alloc(512 * 4);
    int* bscan = (int*)alloc(512 * 4);
    int* sorted_src = (int*)alloc((size_t)E * 4);
    float* h1 = (float*)alloc((size_t)N * 128 * 4);

    int eb = (E + 255) / 256;
    int nb = (N + 255) / 256;  // 391 <= 512, fits scan_top
    int gb = (N + 63) / 64;

    zero_kernel<<<nb, 256, 0, stream>>>(counts, N);
    hist_kernel<<<eb, 256, 0, stream>>>(eidx, E, counts);
    scan_block_kernel<<<nb, 256, 0, stream>>>(counts, offsets, bsum, N);
    scan_top_kernel<<<1, 512, 0, stream>>>(bsum, bscan, nb, offsets, N, E);
    scan_add_kernel<<<nb, 256, 0, stream>>>(offsets, bscan, counts, N);  // counts -> cursor
    scatter_kernel<<<eb, 256, 0, stream>>>(eidx, E, counts, sorted_src);

    gin_layer_kernel<64, 128, 128, true>
        <<<gb, 256, 0, stream>>>(x, offsets, sorted_src, eps1, W1a, b1a, W1b, b1b, h1, N);
    gin_layer_kernel<128, 128, 64, false>
        <<<gb, 256, 0, stream>>>(h1, offsets, sorted_src, eps2, W2a, b2a, W2b, b2b, out, N);
}

// Round 7
// 485.824 us; speedup vs baseline: 2.5369x; 1.9275x over previous
//
#include <hip/hip_runtime.h>
#include <cstdint>

// ---------------- helpers ----------------

__global__ void zero_kernel(int* __restrict__ p, int n) {
    int i = blockIdx.x * 256 + threadIdx.x;
    if (i < n) p[i] = 0;
}

// ---------------- CSR build (by dst), reused for both layers ----------------
// edge_index arrives as int32 (JAX default x64=False).

__global__ void hist_kernel(const int* __restrict__ eidx, int E, int* __restrict__ counts) {
    int e = blockIdx.x * 256 + threadIdx.x;
    if (e < E) atomicAdd(&counts[eidx[E + e]], 1);
}

__global__ void scan_block_kernel(const int* __restrict__ counts, int* __restrict__ offsets,
                                  int* __restrict__ bsum, int n) {
    __shared__ int s[256];
    int i = blockIdx.x * 256 + threadIdx.x;
    int v = (i < n) ? counts[i] : 0;
    s[threadIdx.x] = v;
    __syncthreads();
    for (int d = 1; d < 256; d <<= 1) {
        int t = (threadIdx.x >= d) ? s[threadIdx.x - d] : 0;
        __syncthreads();
        s[threadIdx.x] += t;
        __syncthreads();
    }
    if (i < n) offsets[i] = s[threadIdx.x] - v;  // exclusive within block
    if (threadIdx.x == 255) bsum[blockIdx.x] = s[255];
}

__global__ void scan_top_kernel(const int* __restrict__ bsum, int* __restrict__ bscan,
                                int nb, int* __restrict__ offsets, int n, int E) {
    __shared__ int s[512];
    int v = (threadIdx.x < nb) ? bsum[threadIdx.x] : 0;
    s[threadIdx.x] = v;
    __syncthreads();
    for (int d = 1; d < 512; d <<= 1) {
        int t = (threadIdx.x >= d) ? s[threadIdx.x - d] : 0;
        __syncthreads();
        s[threadIdx.x] += t;
        __syncthreads();
    }
    if (threadIdx.x < nb) bscan[threadIdx.x] = s[threadIdx.x] - v;
    if (threadIdx.x == 0) offsets[n] = E;
}

__global__ void scan_add_kernel(int* __restrict__ offsets, const int* __restrict__ bscan,
                                int* __restrict__ cursor, int n) {
    int i = blockIdx.x * 256 + threadIdx.x;
    if (i < n) {
        int o = offsets[i] + bscan[blockIdx.x];
        offsets[i] = o;
        cursor[i] = o;
    }
}

__global__ void scatter_kernel(const int* __restrict__ eidx, int E,
                               int* __restrict__ cursor, int* __restrict__ sorted_src) {
    int e = blockIdx.x * 256 + threadIdx.x;
    if (e < E) {
        int pos = atomicAdd(&cursor[eidx[E + e]], 1);
        sorted_src[pos] = eidx[e];
    }
}

// ---------------- Fused GIN layer: aggregate + 2-layer MLP (fp32) ----------------
// Block = 256 threads (4 waves), 64 nodes per block.
// Phase A: wave w gathers for nodes [16w,16w+16); lane = feature; edge loop
//          unrolled x4. Result transposed into LDS, row stride 65 (2-way = free).
// Phase B/C: thread = (node = lane, out-quarter = wave).
// CRITICAL FIX vs R5: the weight offset uses readfirstlane(wave) so the address
// is PROVABLY wave-uniform -> compiler emits s_load (scalar pipe) instead of
// per-lane global_load. R4/R5 were bound by 6144 broadcast VMEM loads/thread
// (layer1 == layer2 time == 6144 weight fetches; VALUBusy 12.5%).

template <int KIN, int KMID, int KOUT, bool RELU_OUT>
__global__ __launch_bounds__(256) void gin_layer_kernel(
    const float* __restrict__ h, const int* __restrict__ offs, const int* __restrict__ srcs,
    const float* __restrict__ eps, const float* __restrict__ Wa, const float* __restrict__ ba,
    const float* __restrict__ Wb, const float* __restrict__ bb, float* __restrict__ out, int n) {
    constexpr int ST = 65;  // bank = (row + m) % 32 -> worst 2-way (free)
    constexpr int LROWS = (KIN > KMID ? KIN : KMID);
    __shared__ float lds[LROWS * ST];
    const int tid = threadIdx.x;
    const int lane = tid & 63;
    const int wave = tid >> 6;
    const int base = blockIdx.x * 64;
    const float scale = 1.0f + eps[0];

    // ---- Phase A: gather + transpose, 16 nodes per wave ----
    for (int mi = 0; mi < 16; ++mi) {
        const int m = wave * 16 + mi;
        const int node = base + m;
        if (node >= n) break;
        const int e0 = offs[node], e1 = offs[node + 1];
        if (KIN == 64) {
            float acc = scale * h[(size_t)node * 64 + lane];
            float a0 = 0.f, a1 = 0.f, a2 = 0.f, a3 = 0.f;
            int e = e0;
            for (; e + 4 <= e1; e += 4) {
                int s0 = srcs[e], s1 = srcs[e + 1], s2 = srcs[e + 2], s3 = srcs[e + 3];
                a0 += h[(size_t)s0 * 64 + lane];
                a1 += h[(size_t)s1 * 64 + lane];
                a2 += h[(size_t)s2 * 64 + lane];
                a3 += h[(size_t)s3 * 64 + lane];
            }
            for (; e < e1; ++e) acc += h[(size_t)srcs[e] * 64 + lane];
            acc += (a0 + a1) + (a2 + a3);
            lds[lane * ST + m] = acc;
        } else {  // KIN == 128: lane covers features {lane, lane+64}
            const float* hr = h + (size_t)node * 128;
            float accx = scale * hr[lane];
            float accy = scale * hr[64 + lane];
            float x0 = 0.f, x1 = 0.f, x2 = 0.f, x3 = 0.f;
            float y0 = 0.f, y1 = 0.f, y2 = 0.f, y3 = 0.f;
            int e = e0;
            for (; e + 4 <= e1; e += 4) {
                const float* r0 = h + (size_t)srcs[e] * 128;
                const float* r1 = h + (size_t)srcs[e + 1] * 128;
                const float* r2 = h + (size_t)srcs[e + 2] * 128;
                const float* r3 = h + (size_t)srcs[e + 3] * 128;
                x0 += r0[lane];
                y0 += r0[64 + lane];
                x1 += r1[lane];
                y1 += r1[64 + lane];
                x2 += r2[lane];
                y2 += r2[64 + lane];
                x3 += r3[lane];
                y3 += r3[64 + lane];
            }
            for (; e < e1; ++e) {
                const float* r = h + (size_t)srcs[e] * 128;
                accx += r[lane];
                accy += r[64 + lane];
            }
            accx += (x0 + x1) + (x2 + x3);
            accy += (y0 + y1) + (y2 + y3);
            lds[lane * ST + m] = accx;
            lds[(64 + lane) * ST + m] = accy;
        }
    }
    __syncthreads();

    // Provably wave-uniform quarter index -> scalar (s_load) weight fetches.
    const int wq = __builtin_amdgcn_readfirstlane(wave);

    // ---- Phase B: t = relu(z @ Wa + ba); thread = (node=lane, quarter=wq) ----
    const int m = lane;
    const int node = base + m;
    constexpr int JB = KMID / 4;
    float t[JB];
#pragma unroll
    for (int j = 0; j < JB; ++j) t[j] = 0.0f;
#pragma unroll 2
    for (int k = 0; k < KIN; ++k) {
        const float zk = lds[k * ST + m];
        const float* wrow = Wa + k * KMID + wq * JB;
#pragma unroll
        for (int j = 0; j < JB; ++j) t[j] = __builtin_fmaf(zk, wrow[j], t[j]);
    }
#pragma unroll
    for (int j = 0; j < JB; ++j) t[j] = fmaxf(t[j] + ba[wq * JB + j], 0.0f);

    __syncthreads();  // all z reads done; reuse LDS for t
#pragma unroll
    for (int j = 0; j < JB; ++j) lds[(wq * JB + j) * ST + m] = t[j];
    __syncthreads();

    // ---- Phase C: out = t @ Wb + bb (+ optional relu) ----
    constexpr int JC = KOUT / 4;
    float o[JC];
#pragma unroll
    for (int j = 0; j < JC; ++j) o[j] = 0.0f;
#pragma unroll 2
    for (int k = 0; k < KMID; ++k) {
        const float tk = lds[k * ST + m];
        const float* wrow = Wb + k * KOUT + wq * JC;
#pragma unroll
        for (int j = 0; j < JC; ++j) o[j] = __builtin_fmaf(tk, wrow[j], o[j]);
    }

    if (node < n) {
        float4* orow = (float4*)(out + (size_t)node * KOUT + wq * JC);
#pragma unroll
        for (int j4 = 0; j4 < JC / 4; ++j4) {
            float4 v;
            v.x = o[4 * j4 + 0] + bb[wq * JC + 4 * j4 + 0];
            v.y = o[4 * j4 + 1] + bb[wq * JC + 4 * j4 + 1];
            v.z = o[4 * j4 + 2] + bb[wq * JC + 4 * j4 + 2];
            v.w = o[4 * j4 + 3] + bb[wq * JC + 4 * j4 + 3];
            if (RELU_OUT) {
                v.x = fmaxf(v.x, 0.0f);
                v.y = fmaxf(v.y, 0.0f);
                v.z = fmaxf(v.z, 0.0f);
                v.w = fmaxf(v.w, 0.0f);
            }
            orow[j4] = v;
        }
    }
}

// ---------------- Launch ----------------

extern "C" void kernel_launch(void* const* d_in, const int* in_sizes, int n_in,
                              void* d_out, int out_size, void* d_ws, size_t ws_size,
                              hipStream_t stream) {
    const float* x = (const float*)d_in[0];
    const int* eidx = (const int*)d_in[1];  // int32 (JAX x64 disabled)
    const float* eps1 = (const float*)d_in[2];
    const float* eps2 = (const float*)d_in[3];
    const float* W1a = (const float*)d_in[4];
    const float* b1a = (const float*)d_in[5];
    const float* W1b = (const float*)d_in[6];
    const float* b1b = (const float*)d_in[7];
    const float* W2a = (const float*)d_in[8];
    const float* b2a = (const float*)d_in[9];
    const float* W2b = (const float*)d_in[10];
    const float* b2b = (const float*)d_in[11];
    float* out = (float*)d_out;

    int N = in_sizes[0] / 64;
    int E = in_sizes[1] / 2;

    char* p = (char*)d_ws;
    auto alloc = [&](size_t bytes) {
        char* r = p;
        p += (bytes + 255) & ~(size_t)255;
        return r;
    };
    int* counts = (int*)alloc((size_t)N * 4);  // reused as cursor after scan
    int* offsets = (int*)alloc((size_t)(N + 1) * 4);
    int* bsum = (int*)alloc(512 * 4);
    int* bscan = (int*)alloc(512 * 4);
    int* sorted_src = (int*)alloc((size_t)E * 4);
    float* h1 = (float*)alloc((size_t)N * 128 * 4);

    int eb = (E + 255) / 256;
    int nb = (N + 255) / 256;  // 391 <= 512, fits scan_top
    int gb = (N + 63) / 64;

    zero_kernel<<<nb, 256, 0, stream>>>(counts, N);
    hist_kernel<<<eb, 256, 0, stream>>>(eidx, E, counts);
    scan_block_kernel<<<nb, 256, 0, stream>>>(counts, offsets, bsum, N);
    scan_top_kernel<<<1, 512, 0, stream>>>(bsum, bscan, nb, offsets, N, E);
    scan_add_kernel<<<nb, 256, 0, stream>>>(offsets, bscan, counts, N);  // counts -> cursor
    scatter_kernel<<<eb, 256, 0, stream>>>(eidx, E, counts, sorted_src);

    gin_layer_kernel<64, 128, 128, true>
        <<<gb, 256, 0, stream>>>(x, offsets, sorted_src, eps1, W1a, b1a, W1b, b1b, h1, N);
    gin_layer_kernel<128, 128, 64, false>
        <<<gb, 256, 0, stream>>>(h1, offsets, sorted_src, eps2, W2a, b2a, W2b, b2b, out, N);
}

// Round 8
// 442.562 us; speedup vs baseline: 2.7849x; 1.0978x over previous
//
#include <hip/hip_runtime.h>
#include <cstdint>

// ---------------- helpers ----------------

__global__ void zero_kernel(int* __restrict__ p, int n) {
    int i = blockIdx.x * 256 + threadIdx.x;
    if (i < n) p[i] = 0;
}

// ---------------- CSR build (by dst), reused for both layers ----------------
// edge_index arrives as int32 (JAX default x64=False).

__global__ void hist_kernel(const int* __restrict__ eidx, int E, int* __restrict__ counts) {
    int e = blockIdx.x * 256 + threadIdx.x;
    if (e < E) atomicAdd(&counts[eidx[E + e]], 1);
}

__global__ void scan_block_kernel(const int* __restrict__ counts, int* __restrict__ offsets,
                                  int* __restrict__ bsum, int n) {
    __shared__ int s[256];
    int i = blockIdx.x * 256 + threadIdx.x;
    int v = (i < n) ? counts[i] : 0;
    s[threadIdx.x] = v;
    __syncthreads();
    for (int d = 1; d < 256; d <<= 1) {
        int t = (threadIdx.x >= d) ? s[threadIdx.x - d] : 0;
        __syncthreads();
        s[threadIdx.x] += t;
        __syncthreads();
    }
    if (i < n) offsets[i] = s[threadIdx.x] - v;  // exclusive within block
    if (threadIdx.x == 255) bsum[blockIdx.x] = s[255];
}

__global__ void scan_top_kernel(const int* __restrict__ bsum, int* __restrict__ bscan,
                                int nb, int* __restrict__ offsets, int n, int E) {
    __shared__ int s[512];
    int v = (threadIdx.x < nb) ? bsum[threadIdx.x] : 0;
    s[threadIdx.x] = v;
    __syncthreads();
    for (int d = 1; d < 512; d <<= 1) {
        int t = (threadIdx.x >= d) ? s[threadIdx.x - d] : 0;
        __syncthreads();
        s[threadIdx.x] += t;
        __syncthreads();
    }
    if (threadIdx.x < nb) bscan[threadIdx.x] = s[threadIdx.x] - v;
    if (threadIdx.x == 0) offsets[n] = E;
}

__global__ void scan_add_kernel(int* __restrict__ offsets, const int* __restrict__ bscan,
                                int* __restrict__ cursor, int n) {
    int i = blockIdx.x * 256 + threadIdx.x;
    if (i < n) {
        int o = offsets[i] + bscan[blockIdx.x];
        offsets[i] = o;
        cursor[i] = o;
    }
}

__global__ void scatter_kernel(const int* __restrict__ eidx, int E,
                               int* __restrict__ cursor, int* __restrict__ sorted_src) {
    int e = blockIdx.x * 256 + threadIdx.x;
    if (e < E) {
        int pos = atomicAdd(&cursor[eidx[E + e]], 1);
        sorted_src[pos] = eidx[e];
    }
}

// ---------------- Fused GIN layer: aggregate + 2-layer MLP (fp32) ----------------
// Block = 512 threads (8 waves), 64 nodes per block.
// Phase A: wave w gathers for nodes [8w, 8w+8); lane = feature; edge loop
//          unrolled x4. Result transposed into LDS, row stride 65 (2-way = free).
// Phase B/C: thread = (node = lane, out-eighth = wave). Weight offsets go
//          through readfirstlane -> provably wave-uniform -> s_load on the
//          scalar pipe (the R7 fix: 3x speedup over broadcast VMEM loads).
// 512-thread blocks -> 4 blocks/CU (thread cap) x 8 waves = 32 waves/CU = 100%
// occupancy (R7 had 16), and per-wave serial gather chain halves.

template <int KIN, int KMID, int KOUT, bool RELU_OUT>
__global__ __launch_bounds__(512, 8) void gin_layer_kernel(
    const float* __restrict__ h, const int* __restrict__ offs, const int* __restrict__ srcs,
    const float* __restrict__ eps, const float* __restrict__ Wa, const float* __restrict__ ba,
    const float* __restrict__ Wb, const float* __restrict__ bb, float* __restrict__ out, int n) {
    constexpr int ST = 65;  // bank = (row + m) % 32 -> worst 2-way (free)
    constexpr int LROWS = (KIN > KMID ? KIN : KMID);
    constexpr int WAVES = 8;
    __shared__ float lds[LROWS * ST];
    const int tid = threadIdx.x;
    const int lane = tid & 63;
    const int wave = tid >> 6;
    const int base = blockIdx.x * 64;
    const float scale = 1.0f + eps[0];

    // ---- Phase A: gather + transpose, 8 nodes per wave ----
    for (int mi = 0; mi < 64 / WAVES; ++mi) {
        const int m = wave * (64 / WAVES) + mi;
        const int node = base + m;
        if (node >= n) break;
        const int e0 = offs[node], e1 = offs[node + 1];
        if (KIN == 64) {
            float acc = scale * h[(size_t)node * 64 + lane];
            float a0 = 0.f, a1 = 0.f, a2 = 0.f, a3 = 0.f;
            int e = e0;
            for (; e + 4 <= e1; e += 4) {
                int s0 = srcs[e], s1 = srcs[e + 1], s2 = srcs[e + 2], s3 = srcs[e + 3];
                a0 += h[(size_t)s0 * 64 + lane];
                a1 += h[(size_t)s1 * 64 + lane];
                a2 += h[(size_t)s2 * 64 + lane];
                a3 += h[(size_t)s3 * 64 + lane];
            }
            for (; e < e1; ++e) acc += h[(size_t)srcs[e] * 64 + lane];
            acc += (a0 + a1) + (a2 + a3);
            lds[lane * ST + m] = acc;
        } else {  // KIN == 128: lane covers features {lane, lane+64}
            const float* hr = h + (size_t)node * 128;
            float accx = scale * hr[lane];
            float accy = scale * hr[64 + lane];
            float x0 = 0.f, x1 = 0.f, x2 = 0.f, x3 = 0.f;
            float y0 = 0.f, y1 = 0.f, y2 = 0.f, y3 = 0.f;
            int e = e0;
            for (; e + 4 <= e1; e += 4) {
                const float* r0 = h + (size_t)srcs[e] * 128;
                const float* r1 = h + (size_t)srcs[e + 1] * 128;
                const float* r2 = h + (size_t)srcs[e + 2] * 128;
                const float* r3 = h + (size_t)srcs[e + 3] * 128;
                x0 += r0[lane];
                y0 += r0[64 + lane];
                x1 += r1[lane];
                y1 += r1[64 + lane];
                x2 += r2[lane];
                y2 += r2[64 + lane];
                x3 += r3[lane];
                y3 += r3[64 + lane];
            }
            for (; e < e1; ++e) {
                const float* r = h + (size_t)srcs[e] * 128;
                accx += r[lane];
                accy += r[64 + lane];
            }
            accx += (x0 + x1) + (x2 + x3);
            accy += (y0 + y1) + (y2 + y3);
            lds[lane * ST + m] = accx;
            lds[(64 + lane) * ST + m] = accy;
        }
    }
    __syncthreads();

    // Provably wave-uniform slice index -> scalar (s_load) weight fetches.
    const int wq = __builtin_amdgcn_readfirstlane(wave);

    // ---- Phase B: t = relu(z @ Wa + ba); thread = (node=lane, eighth=wq) ----
    const int m = lane;
    const int node = base + m;
    constexpr int JB = KMID / WAVES;
    float t[JB];
#pragma unroll
    for (int j = 0; j < JB; ++j) t[j] = 0.0f;
#pragma unroll 2
    for (int k = 0; k < KIN; ++k) {
        const float zk = lds[k * ST + m];
        const float* wrow = Wa + k * KMID + wq * JB;
#pragma unroll
        for (int j = 0; j < JB; ++j) t[j] = __builtin_fmaf(zk, wrow[j], t[j]);
    }
#pragma unroll
    for (int j = 0; j < JB; ++j) t[j] = fmaxf(t[j] + ba[wq * JB + j], 0.0f);

    __syncthreads();  // all z reads done; reuse LDS for t
#pragma unroll
    for (int j = 0; j < JB; ++j) lds[(wq * JB + j) * ST + m] = t[j];
    __syncthreads();

    // ---- Phase C: out = t @ Wb + bb (+ optional relu) ----
    constexpr int JC = KOUT / WAVES;
    float o[JC];
#pragma unroll
    for (int j = 0; j < JC; ++j) o[j] = 0.0f;
#pragma unroll 2
    for (int k = 0; k < KMID; ++k) {
        const float tk = lds[k * ST + m];
        const float* wrow = Wb + k * KOUT + wq * JC;
#pragma unroll
        for (int j = 0; j < JC; ++j) o[j] = __builtin_fmaf(tk, wrow[j], o[j]);
    }

    if (node < n) {
        float4* orow = (float4*)(out + (size_t)node * KOUT + wq * JC);
#pragma unroll
        for (int j4 = 0; j4 < JC / 4; ++j4) {
            float4 v;
            v.x = o[4 * j4 + 0] + bb[wq * JC + 4 * j4 + 0];
            v.y = o[4 * j4 + 1] + bb[wq * JC + 4 * j4 + 1];
            v.z = o[4 * j4 + 2] + bb[wq * JC + 4 * j4 + 2];
            v.w = o[4 * j4 + 3] + bb[wq * JC + 4 * j4 + 3];
            if (RELU_OUT) {
                v.x = fmaxf(v.x, 0.0f);
                v.y = fmaxf(v.y, 0.0f);
                v.z = fmaxf(v.z, 0.0f);
                v.w = fmaxf(v.w, 0.0f);
            }
            orow[j4] = v;
        }
    }
}

// ---------------- Launch ----------------

extern "C" void kernel_launch(void* const* d_in, const int* in_sizes, int n_in,
                              void* d_out, int out_size, void* d_ws, size_t ws_size,
                              hipStream_t stream) {
    const float* x = (const float*)d_in[0];
    const int* eidx = (const int*)d_in[1];  // int32 (JAX x64 disabled)
    const float* eps1 = (const float*)d_in[2];
    const float* eps2 = (const float*)d_in[3];
    const float* W1a = (const float*)d_in[4];
    const float* b1a = (const float*)d_in[5];
    const float* W1b = (const float*)d_in[6];
    const float* b1b = (const float*)d_in[7];
    const float* W2a = (const float*)d_in[8];
    const float* b2a = (const float*)d_in[9];
    const float* W2b = (const float*)d_in[10];
    const float* b2b = (const float*)d_in[11];
    float* out = (float*)d_out;

    int N = in_sizes[0] / 64;
    int E = in_sizes[1] / 2;

    char* p = (char*)d_ws;
    auto alloc = [&](size_t bytes) {
        char* r = p;
        p += (bytes + 255) & ~(size_t)255;
        return r;
    };
    int* counts = (int*)alloc((size_t)N * 4);  // reused as cursor after scan
    int* offsets = (int*)alloc((size_t)(N + 1) * 4);
    int* bsum = (int*)alloc(512 * 4);
    int* bscan = (int*)alloc(512 * 4);
    int* sorted_src = (int*)alloc((size_t)E * 4);
    float* h1 = (float*)alloc((size_t)N * 128 * 4);

    int eb = (E + 255) / 256;
    int nb = (N + 255) / 256;  // 391 <= 512, fits scan_top
    int gb = (N + 63) / 64;

    zero_kernel<<<nb, 256, 0, stream>>>(counts, N);
    hist_kernel<<<eb, 256, 0, stream>>>(eidx, E, counts);
    scan_block_kernel<<<nb, 256, 0, stream>>>(counts, offsets, bsum, N);
    scan_top_kernel<<<1, 512, 0, stream>>>(bsum, bscan, nb, offsets, N, E);
    scan_add_kernel<<<nb, 256, 0, stream>>>(offsets, bscan, counts, N);  // counts -> cursor
    scatter_kernel<<<eb, 256, 0, stream>>>(eidx, E, counts, sorted_src);

    gin_layer_kernel<64, 128, 128, true>
        <<<gb, 512, 0, stream>>>(x, offsets, sorted_src, eps1, W1a, b1a, W1b, b1b, h1, N);
    gin_layer_kernel<128, 128, 64, false>
        <<<gb, 512, 0, stream>>>(h1, offsets, sorted_src, eps2, W2a, b2a, W2b, b2b, out, N);
}

// Round 9
// 413.332 us; speedup vs baseline: 2.9819x; 1.0707x over previous
//
#include <hip/hip_runtime.h>
#include <cstdint>

// ---------------- helpers ----------------

__global__ void zero_kernel(int* __restrict__ p, int n) {
    int i = blockIdx.x * 256 + threadIdx.x;
    if (i < n) p[i] = 0;
}

// ---------------- CSR build (by dst), reused for both layers ----------------
// edge_index arrives as int32 (JAX default x64=False).

__global__ void hist_kernel(const int* __restrict__ eidx, int E, int* __restrict__ counts) {
    int e = blockIdx.x * 256 + threadIdx.x;
    if (e < E) atomicAdd(&counts[eidx[E + e]], 1);
}

__global__ void scan_block_kernel(const int* __restrict__ counts, int* __restrict__ offsets,
                                  int* __restrict__ bsum, int n) {
    __shared__ int s[256];
    int i = blockIdx.x * 256 + threadIdx.x;
    int v = (i < n) ? counts[i] : 0;
    s[threadIdx.x] = v;
    __syncthreads();
    for (int d = 1; d < 256; d <<= 1) {
        int t = (threadIdx.x >= d) ? s[threadIdx.x - d] : 0;
        __syncthreads();
        s[threadIdx.x] += t;
        __syncthreads();
    }
    if (i < n) offsets[i] = s[threadIdx.x] - v;  // exclusive within block
    if (threadIdx.x == 255) bsum[blockIdx.x] = s[255];
}

__global__ void scan_top_kernel(const int* __restrict__ bsum, int* __restrict__ bscan,
                                int nb, int* __restrict__ offsets, int n, int E) {
    __shared__ int s[512];
    int v = (threadIdx.x < nb) ? bsum[threadIdx.x] : 0;
    s[threadIdx.x] = v;
    __syncthreads();
    for (int d = 1; d < 512; d <<= 1) {
        int t = (threadIdx.x >= d) ? s[threadIdx.x - d] : 0;
        __syncthreads();
        s[threadIdx.x] += t;
        __syncthreads();
    }
    if (threadIdx.x < nb) bscan[threadIdx.x] = s[threadIdx.x] - v;
    if (threadIdx.x == 0) offsets[n] = E;
}

__global__ void scan_add_kernel(int* __restrict__ offsets, const int* __restrict__ bscan,
                                int* __restrict__ cursor, int n) {
    int i = blockIdx.x * 256 + threadIdx.x;
    if (i < n) {
        int o = offsets[i] + bscan[blockIdx.x];
        offsets[i] = o;
        cursor[i] = o;
    }
}

__global__ void scatter_kernel(const int* __restrict__ eidx, int E,
                               int* __restrict__ cursor, int* __restrict__ sorted_src) {
    int e = blockIdx.x * 256 + threadIdx.x;
    if (e < E) {
        int pos = atomicAdd(&cursor[eidx[E + e]], 1);
        sorted_src[pos] = eidx[e];
    }
}

// ---------------- Fused GIN layer: aggregate + 2-layer MLP (fp32) ----------------
// Block = 512 threads (8 waves), 64 nodes per block.
// Phase A: wave w gathers nodes [8w, 8w+8); node/e0/e1 forced wave-uniform via
//          readfirstlane so edge-index fetches become s_load (scalar pipe) and
//          row gathers use SGPR-base addressing. Edge loop unrolled x8 (KIN=64,
//          8 rows in flight) / x4 float2 (KIN=128, 8 dwordx2 in flight).
// Phase B/C: thread = (node = lane, out-eighth = wave); weights via s_load
//          (readfirstlane, the R7 fix). LDS stride 65.

template <int KIN, int KMID, int KOUT, bool RELU_OUT>
__global__ __launch_bounds__(512, 8) void gin_layer_kernel(
    const float* __restrict__ h, const int* __restrict__ offs, const int* __restrict__ srcs,
    const float* __restrict__ eps, const float* __restrict__ Wa, const float* __restrict__ ba,
    const float* __restrict__ Wb, const float* __restrict__ bb, float* __restrict__ out, int n) {
    constexpr int ST = 65;
    constexpr int LROWS = (KIN > KMID ? KIN : KMID);
    constexpr int WAVES = 8;
    __shared__ float lds[LROWS * ST];
    const int tid = threadIdx.x;
    const int lane = tid & 63;
    const int base = blockIdx.x * 64;
    const float scale = 1.0f + eps[0];

    // Provably wave-uniform wave index (drives scalar addressing everywhere).
    const int wq = __builtin_amdgcn_readfirstlane(tid >> 6);

    // ---- Phase A: gather + transpose, 8 nodes per wave ----
    for (int mi = 0; mi < 64 / WAVES; ++mi) {
        const int m = wq * (64 / WAVES) + mi;
        const int node = base + m;
        if (node >= n) break;
        const int e0 = __builtin_amdgcn_readfirstlane(offs[node]);
        const int e1 = __builtin_amdgcn_readfirstlane(offs[node + 1]);
        if (KIN == 64) {
            float acc = scale * h[(size_t)node * 64 + lane];
            float a0 = 0.f, a1 = 0.f, a2 = 0.f, a3 = 0.f;
            float a4 = 0.f, a5 = 0.f, a6 = 0.f, a7 = 0.f;
            int e = e0;
            for (; e + 8 <= e1; e += 8) {
                int s0 = srcs[e + 0], s1 = srcs[e + 1], s2 = srcs[e + 2], s3 = srcs[e + 3];
                int s4 = srcs[e + 4], s5 = srcs[e + 5], s6 = srcs[e + 6], s7 = srcs[e + 7];
                a0 += h[(size_t)s0 * 64 + lane];
                a1 += h[(size_t)s1 * 64 + lane];
                a2 += h[(size_t)s2 * 64 + lane];
                a3 += h[(size_t)s3 * 64 + lane];
                a4 += h[(size_t)s4 * 64 + lane];
                a5 += h[(size_t)s5 * 64 + lane];
                a6 += h[(size_t)s6 * 64 + lane];
                a7 += h[(size_t)s7 * 64 + lane];
            }
            for (; e + 4 <= e1; e += 4) {
                int s0 = srcs[e + 0], s1 = srcs[e + 1], s2 = srcs[e + 2], s3 = srcs[e + 3];
                a0 += h[(size_t)s0 * 64 + lane];
                a1 += h[(size_t)s1 * 64 + lane];
                a2 += h[(size_t)s2 * 64 + lane];
                a3 += h[(size_t)s3 * 64 + lane];
            }
            for (; e < e1; ++e) acc += h[(size_t)srcs[e] * 64 + lane];
            acc += ((a0 + a1) + (a2 + a3)) + ((a4 + a5) + (a6 + a7));
            lds[lane * ST + m] = acc;
        } else {  // KIN == 128: float2 rows; lane covers features {2*lane, 2*lane+1}
            const float2* h2 = (const float2*)h;
            float2 a = h2[(size_t)node * 64 + lane];
            float ax = scale * a.x, ay = scale * a.y;
            float x0 = 0.f, x1 = 0.f, x2 = 0.f, x3 = 0.f;
            float y0 = 0.f, y1 = 0.f, y2 = 0.f, y3 = 0.f;
            int e = e0;
            for (; e + 4 <= e1; e += 4) {
                int s0 = srcs[e + 0], s1 = srcs[e + 1], s2 = srcs[e + 2], s3 = srcs[e + 3];
                float2 v0 = h2[(size_t)s0 * 64 + lane];
                float2 v1 = h2[(size_t)s1 * 64 + lane];
                float2 v2 = h2[(size_t)s2 * 64 + lane];
                float2 v3 = h2[(size_t)s3 * 64 + lane];
                x0 += v0.x;
                y0 += v0.y;
                x1 += v1.x;
                y1 += v1.y;
                x2 += v2.x;
                y2 += v2.y;
                x3 += v3.x;
                y3 += v3.y;
            }
            for (; e < e1; ++e) {
                float2 v = h2[(size_t)srcs[e] * 64 + lane];
                ax += v.x;
                ay += v.y;
            }
            ax += (x0 + x1) + (x2 + x3);
            ay += (y0 + y1) + (y2 + y3);
            // feature rows 2*lane and 2*lane+1 (4-way bank alias on 2 writes: negligible)
            lds[(2 * lane) * ST + m] = ax;
            lds[(2 * lane + 1) * ST + m] = ay;
        }
    }
    __syncthreads();

    // ---- Phase B: t = relu(z @ Wa + ba); thread = (node=lane, eighth=wq) ----
    const int m = lane;
    const int node = base + m;
    constexpr int JB = KMID / WAVES;
    float t[JB];
#pragma unroll
    for (int j = 0; j < JB; ++j) t[j] = 0.0f;
#pragma unroll 2
    for (int k = 0; k < KIN; ++k) {
        const float zk = lds[k * ST + m];
        const float* wrow = Wa + k * KMID + wq * JB;
#pragma unroll
        for (int j = 0; j < JB; ++j) t[j] = __builtin_fmaf(zk, wrow[j], t[j]);
    }
#pragma unroll
    for (int j = 0; j < JB; ++j) t[j] = fmaxf(t[j] + ba[wq * JB + j], 0.0f);

    __syncthreads();  // all z reads done; reuse LDS for t
#pragma unroll
    for (int j = 0; j < JB; ++j) lds[(wq * JB + j) * ST + m] = t[j];
    __syncthreads();

    // ---- Phase C: out = t @ Wb + bb (+ optional relu) ----
    constexpr int JC = KOUT / WAVES;
    float o[JC];
#pragma unroll
    for (int j = 0; j < JC; ++j) o[j] = 0.0f;
#pragma unroll 2
    for (int k = 0; k < KMID; ++k) {
        const float tk = lds[k * ST + m];
        const float* wrow = Wb + k * KOUT + wq * JC;
#pragma unroll
        for (int j = 0; j < JC; ++j) o[j] = __builtin_fmaf(tk, wrow[j], o[j]);
    }

    if (node < n) {
        float4* orow = (float4*)(out + (size_t)node * KOUT + wq * JC);
#pragma unroll
        for (int j4 = 0; j4 < JC / 4; ++j4) {
            float4 v;
            v.x = o[4 * j4 + 0] + bb[wq * JC + 4 * j4 + 0];
            v.y = o[4 * j4 + 1] + bb[wq * JC + 4 * j4 + 1];
            v.z = o[4 * j4 + 2] + bb[wq * JC + 4 * j4 + 2];
            v.w = o[4 * j4 + 3] + bb[wq * JC + 4 * j4 + 3];
            if (RELU_OUT) {
                v.x = fmaxf(v.x, 0.0f);
                v.y = fmaxf(v.y, 0.0f);
                v.z = fmaxf(v.z, 0.0f);
                v.w = fmaxf(v.w, 0.0f);
            }
            orow[j4] = v;
        }
    }
}

// ---------------- Launch ----------------

extern "C" void kernel_launch(void* const* d_in, const int* in_sizes, int n_in,
                              void* d_out, int out_size, void* d_ws, size_t ws_size,
                              hipStream_t stream) {
    const float* x = (const float*)d_in[0];
    const int* eidx = (const int*)d_in[1];  // int32 (JAX x64 disabled)
    const float* eps1 = (const float*)d_in[2];
    const float* eps2 = (const float*)d_in[3];
    const float* W1a = (const float*)d_in[4];
    const float* b1a = (const float*)d_in[5];
    const float* W1b = (const float*)d_in[6];
    const float* b1b = (const float*)d_in[7];
    const float* W2a = (const float*)d_in[8];
    const float* b2a = (const float*)d_in[9];
    const float* W2b = (const float*)d_in[10];
    const float* b2b = (const float*)d_in[11];
    float* out = (float*)d_out;

    int N = in_sizes[0] / 64;
    int E = in_sizes[1] / 2;

    char* p = (char*)d_ws;
    auto alloc = [&](size_t bytes) {
        char* r = p;
        p += (bytes + 255) & ~(size_t)255;
        return r;
    };
    int* counts = (int*)alloc((size_t)N * 4);  // reused as cursor after scan
    int* offsets = (int*)alloc((size_t)(N + 1) * 4);
    int* bsum = (int*)alloc(512 * 4);
    int* bscan = (int*)alloc(512 * 4);
    int* sorted_src = (int*)alloc((size_t)E * 4);
    float* h1 = (float*)alloc((size_t)N * 128 * 4);

    int eb = (E + 255) / 256;
    int nb = (N + 255) / 256;  // 391 <= 512, fits scan_top
    int gb = (N + 63) / 64;

    zero_kernel<<<nb, 256, 0, stream>>>(counts, N);
    hist_kernel<<<eb, 256, 0, stream>>>(eidx, E, counts);
    scan_block_kernel<<<nb, 256, 0, stream>>>(counts, offsets, bsum, N);
    scan_top_kernel<<<1, 512, 0, stream>>>(bsum, bscan, nb, offsets, N, E);
    scan_add_kernel<<<nb, 256, 0, stream>>>(offsets, bscan, counts, N);  // counts -> cursor
    scatter_kernel<<<eb, 256, 0, stream>>>(eidx, E, counts, sorted_src);

    gin_layer_kernel<64, 128, 128, true>
        <<<gb, 512, 0, stream>>>(x, offsets, sorted_src, eps1, W1a, b1a, W1b, b1b, h1, N);
    gin_layer_kernel<128, 128, 64, false>
        <<<gb, 512, 0, stream>>>(h1, offsets, sorted_src, eps2, W2a, b2a, W2b, b2b, out, N);
}